// Round 5
// baseline (207.333 us; speedup 1.0000x reference)
//
#include <hip/hip_runtime.h>
#include <math.h>

#define NBLK 256

typedef __attribute__((ext_vector_type(8))) short short8v;  // 8 bf16 (4 VGPR)
typedef __attribute__((ext_vector_type(4))) float f32x4;

__device__ __forceinline__ unsigned cvt_pk_bf16(float lo, float hi) {
    unsigned r;
    asm("v_cvt_pk_bf16_f32 %0, %1, %2" : "=v"(r) : "v"(lo), "v"(hi));
    return r;
}
__device__ __forceinline__ float bf_lo(unsigned u) { return __uint_as_float(u << 16); }
__device__ __forceinline__ float bf_hi(unsigned u) { return __uint_as_float(u & 0xffff0000u); }

__device__ __forceinline__ float fast_tanh(float x) {
    float cx = fminf(fmaxf(x, -15.f), 15.f);
    float e = __expf(2.f * cx);
    return (e - 1.f) / (e + 1.f);
}

// ---------- preprocessing: CSR by dst ----------

__global__ __launch_bounds__(NBLK) void zero_k(int* p, int n) {
    int i = blockIdx.x * blockDim.x + threadIdx.x;
    if (i < n) p[i] = 0;
}

__global__ __launch_bounds__(NBLK) void count_k(const int* __restrict__ dst, int E, int* __restrict__ cnt) {
    int e = blockIdx.x * blockDim.x + threadIdx.x;
    if (e < E) atomicAdd(&cnt[dst[e]], 1);
}

__global__ __launch_bounds__(NBLK) void scan1_k(const int* __restrict__ cnt, int n,
                                                int* __restrict__ off, int* __restrict__ bsum) {
    __shared__ int ls[NBLK];
    int base = blockIdx.x * 1024 + threadIdx.x * 4;
    int v[4]; int s = 0;
#pragma unroll
    for (int i = 0; i < 4; ++i) {
        int idx = base + i;
        v[i] = (idx < n) ? cnt[idx] : 0;
        s += v[i];
    }
    ls[threadIdx.x] = s;
    __syncthreads();
    for (int o = 1; o < NBLK; o <<= 1) {
        int t = (threadIdx.x >= (unsigned)o) ? ls[threadIdx.x - o] : 0;
        __syncthreads();
        ls[threadIdx.x] += t;
        __syncthreads();
    }
    int run = ls[threadIdx.x] - s;
#pragma unroll
    for (int i = 0; i < 4; ++i) {
        int idx = base + i;
        if (idx < n) off[idx] = run;
        run += v[i];
    }
    if (threadIdx.x == NBLK - 1) bsum[blockIdx.x] = ls[NBLK - 1];
}

__global__ void scan2_k(int* bsum, int nb) {
    __shared__ int ls[128];
    int t = threadIdx.x;
    int v = (t < nb) ? bsum[t] : 0;
    ls[t] = v;
    __syncthreads();
    for (int o = 1; o < 128; o <<= 1) {
        int tv = (t >= o) ? ls[t - o] : 0;
        __syncthreads();
        ls[t] += tv;
        __syncthreads();
    }
    if (t < nb) bsum[t] = ls[t] - v;
}

__global__ __launch_bounds__(NBLK) void scan3_k(int* __restrict__ off, const int* __restrict__ bsum,
                                                const int* __restrict__ cnt, int* __restrict__ cursor,
                                                float* __restrict__ dinv, int n) {
    int i = blockIdx.x * blockDim.x + threadIdx.x;
    if (i < n) {
        int o = off[i] + bsum[i >> 10];
        off[i] = o;
        cursor[i] = o;                           // fill cursor starts at bucket base
        dinv[i] = rsqrtf((float)(cnt[i] + 1));   // deg includes self-loop
    }
}

// fill: only src index needs to be scattered (norm folded into g rows).
__global__ __launch_bounds__(NBLK) void fill_k(const int* __restrict__ src, const int* __restrict__ dst, int E,
                                               int* __restrict__ cursor, int* __restrict__ srcs) {
    int e = blockIdx.x * blockDim.x + threadIdx.x;
    if (e >= E) return;
    int idx = atomicAdd(&cursor[dst[e]], 1);
    srcs[idx] = src[e];
}

// cast + transpose both weight matrices: Wt[col][k] bf16 (128x128 each)
__global__ __launch_bounds__(NBLK) void wcast_k(const float* __restrict__ W1, const float* __restrict__ W2,
                                                ushort* __restrict__ Wt1, ushort* __restrict__ Wt2) {
    int i = blockIdx.x * blockDim.x + threadIdx.x;   // 0..32767
    int which = i >> 14;
    int idx = i & 16383;
    const float* W = which ? W2 : W1;
    ushort* Wt = which ? Wt2 : Wt1;
    int k = idx >> 7, c = idx & 127;
    float v = W[idx];
    Wt[c * 128 + k] = (ushort)(cvt_pk_bf16(v, v) & 0xffffu);
}

// ---------- GEMM: Gb(bf16) = dinv[row] * (Xin @ W) via MFMA 16x16x32 bf16 ----------
// block 256 = 4 waves; block tile 64 rows; wave tile 16 rows x 128 cols.
// B-frags (all of W) resident in registers, loaded once per wave; grid-stride over tiles.
// X staged coalesced -> (cvt) -> XOR-swizzled LDS (conflict-free b128 write+read).
// D layout: col = lane&15, row = (lane>>4)*4 + reg  [m89-verified].

template<int CVT>
__global__ __launch_bounds__(NBLK, 2) void gemm_mfma_k(const void* __restrict__ Xin,
                                                       const ushort* __restrict__ Wt,
                                                       const float* __restrict__ dinv,
                                                       ushort* __restrict__ Gb, int nrows, int nbt) {
    __shared__ unsigned Xls[64 * 64];   // 64 rows x 16 units(8 bf16) x 4 uint, swizzled; 16KB
    const int t = threadIdx.x;
    const int lane = t & 63;
    const int wv = t >> 6;
    const int l15 = lane & 15;
    const int g = lane >> 4;

    short8v B[4][8];
#pragma unroll
    for (int ks = 0; ks < 4; ++ks)
#pragma unroll
        for (int nt = 0; nt < 8; ++nt) {
            int col = nt * 16 + l15;
            int k0 = ks * 32 + g * 8;
            B[ks][nt] = *(const short8v*)&Wt[col * 128 + k0];
        }

    for (int bt = blockIdx.x; bt < nbt; bt += gridDim.x) {
        int row0 = bt * 64;
        __syncthreads();   // previous iteration's frag reads complete
        {
            int r = t >> 2;
            int rg = row0 + r;
#pragma unroll
            for (int j = 0; j < 4; ++j) {
                int u = (t & 3) + 4 * j;
                uint4 val;
                if (CVT) {
                    float4 f0 = make_float4(0.f,0.f,0.f,0.f), f1 = f0;
                    if (rg < nrows) {
                        const float4* Xv = (const float4*)Xin;
                        f0 = Xv[(size_t)rg * 32 + u * 2];
                        f1 = Xv[(size_t)rg * 32 + u * 2 + 1];
                    }
                    val.x = cvt_pk_bf16(f0.x, f0.y); val.y = cvt_pk_bf16(f0.z, f0.w);
                    val.z = cvt_pk_bf16(f1.x, f1.y); val.w = cvt_pk_bf16(f1.z, f1.w);
                } else {
                    val = make_uint4(0u,0u,0u,0u);
                    if (rg < nrows) val = ((const uint4*)Xin)[(size_t)rg * 16 + u];
                }
                *(uint4*)&Xls[r * 64 + ((u ^ (r & 15)) << 2)] = val;
            }
        }
        __syncthreads();

        short8v A[4];
#pragma unroll
        for (int ks = 0; ks < 4; ++ks) {
            int r = wv * 16 + l15;
            int u = ks * 4 + g;
            A[ks] = *(short8v*)&Xls[r * 64 + ((u ^ l15) << 2)];
        }

        f32x4 acc[8];
#pragma unroll
        for (int nt = 0; nt < 8; ++nt) acc[nt] = (f32x4){0.f, 0.f, 0.f, 0.f};
#pragma unroll
        for (int ks = 0; ks < 4; ++ks)
#pragma unroll
            for (int nt = 0; nt < 8; ++nt)
                acc[nt] = __builtin_amdgcn_mfma_f32_16x16x32_bf16(A[ks], B[ks][nt], acc[nt], 0, 0, 0);

        int trow0 = row0 + wv * 16;
        float dv[4];
#pragma unroll
        for (int q = 0; q < 4; ++q) {
            int row = trow0 + g * 4 + q;
            dv[q] = (row < nrows) ? dinv[row] : 0.f;
        }
#pragma unroll
        for (int nt = 0; nt < 8; ++nt)
#pragma unroll
            for (int q = 0; q < 4; ++q) {
                int row = trow0 + g * 4 + q;
                if (row < nrows) {
                    float val = acc[nt][q] * dv[q];
                    Gb[(size_t)row * 128 + nt * 16 + l15] =
                        (ushort)(cvt_pk_bf16(val, val) & 0xffffu);
                }
            }
    }
}

// ---------- aggregate (bf16 gather, norm-free) ----------
// out[n] = dinv[n] * (g[n] + sum_{e: dst=n} g[src]) + b, opt tanh.
// 8 nodes/wave, 8 lanes/node; lane il owns uint4 units {il, il+8}.
// unroll x4 -> 8 b128 gathers in flight per lane; tail slots gather own row (L1-hot) with weight 0.

#define UPK_FMA(u4, nm, A) { \
    A[0] = fmaf(bf_lo((u4).x), (nm), A[0]); A[1] = fmaf(bf_hi((u4).x), (nm), A[1]); \
    A[2] = fmaf(bf_lo((u4).y), (nm), A[2]); A[3] = fmaf(bf_hi((u4).y), (nm), A[3]); \
    A[4] = fmaf(bf_lo((u4).z), (nm), A[4]); A[5] = fmaf(bf_hi((u4).z), (nm), A[5]); \
    A[6] = fmaf(bf_lo((u4).w), (nm), A[6]); A[7] = fmaf(bf_hi((u4).w), (nm), A[7]); }

template<int OUT_BF16>
__global__ __launch_bounds__(NBLK) void aggregate_k(const ushort* __restrict__ Gb,
                                                    const int* __restrict__ off, const int* __restrict__ cnt,
                                                    const int* __restrict__ srcs,
                                                    const float* __restrict__ dinv, const float* __restrict__ bias,
                                                    void* __restrict__ outp, int n, int apply_tanh) {
    int node = (blockIdx.x * blockDim.x + threadIdx.x) >> 3;
    if (node >= n) return;
    int il = threadIdx.x & 7;

    const uint4* Gv = (const uint4*)Gb;   // 16 uint4 per row
    size_t rb = (size_t)node * 16;
    uint4 s0 = Gv[rb + il], s1 = Gv[rb + 8 + il];
    float acc[16] = {
        bf_lo(s0.x), bf_hi(s0.x), bf_lo(s0.y), bf_hi(s0.y),
        bf_lo(s0.z), bf_hi(s0.z), bf_lo(s0.w), bf_hi(s0.w),
        bf_lo(s1.x), bf_hi(s1.x), bf_lo(s1.y), bf_hi(s1.y),
        bf_lo(s1.z), bf_hi(s1.z), bf_lo(s1.w), bf_hi(s1.w)
    };

    int e0 = off[node];
    int deg = cnt[node];
    for (int b = 0; b < deg; b += 4) {
        int sidx[4]; float nm[4];
#pragma unroll
        for (int q = 0; q < 4; ++q) {
            bool v = (b + q) < deg;
            sidx[q] = v ? srcs[e0 + b + q] : node;   // invalid -> own row (L1-hot)
            nm[q] = v ? 1.f : 0.f;
        }
        uint4 g0[4], g1[4];
#pragma unroll
        for (int q = 0; q < 4; ++q) {
            size_t r = (size_t)sidx[q] * 16;
            g0[q] = Gv[r + il];
            g1[q] = Gv[r + 8 + il];
        }
#pragma unroll
        for (int q = 0; q < 4; ++q) {
            UPK_FMA(g0[q], nm[q], acc);
            UPK_FMA(g1[q], nm[q], (acc + 8));
        }
    }

    float dvn = dinv[node];
    float4 b0 = *(const float4*)&bias[il * 8];
    float4 b1 = *(const float4*)&bias[il * 8 + 4];
    float4 b2 = *(const float4*)&bias[64 + il * 8];
    float4 b3 = *(const float4*)&bias[64 + il * 8 + 4];
    acc[0]  = fmaf(acc[0],  dvn, b0.x); acc[1]  = fmaf(acc[1],  dvn, b0.y);
    acc[2]  = fmaf(acc[2],  dvn, b0.z); acc[3]  = fmaf(acc[3],  dvn, b0.w);
    acc[4]  = fmaf(acc[4],  dvn, b1.x); acc[5]  = fmaf(acc[5],  dvn, b1.y);
    acc[6]  = fmaf(acc[6],  dvn, b1.z); acc[7]  = fmaf(acc[7],  dvn, b1.w);
    acc[8]  = fmaf(acc[8],  dvn, b2.x); acc[9]  = fmaf(acc[9],  dvn, b2.y);
    acc[10] = fmaf(acc[10], dvn, b2.z); acc[11] = fmaf(acc[11], dvn, b2.w);
    acc[12] = fmaf(acc[12], dvn, b3.x); acc[13] = fmaf(acc[13], dvn, b3.y);
    acc[14] = fmaf(acc[14], dvn, b3.z); acc[15] = fmaf(acc[15], dvn, b3.w);

    if (apply_tanh) {
#pragma unroll
        for (int i = 0; i < 16; ++i) acc[i] = fast_tanh(acc[i]);
    }

    if (OUT_BF16) {
        uint4 o0, o1;
        o0.x = cvt_pk_bf16(acc[0],  acc[1]);  o0.y = cvt_pk_bf16(acc[2],  acc[3]);
        o0.z = cvt_pk_bf16(acc[4],  acc[5]);  o0.w = cvt_pk_bf16(acc[6],  acc[7]);
        o1.x = cvt_pk_bf16(acc[8],  acc[9]);  o1.y = cvt_pk_bf16(acc[10], acc[11]);
        o1.z = cvt_pk_bf16(acc[12], acc[13]); o1.w = cvt_pk_bf16(acc[14], acc[15]);
        uint4* O = (uint4*)outp;
        O[(size_t)node * 16 + il] = o0;
        O[(size_t)node * 16 + 8 + il] = o1;
    } else {
        float* O = (float*)outp;
        *(float4*)&O[(size_t)node * 128 + il * 8]          = make_float4(acc[0], acc[1], acc[2], acc[3]);
        *(float4*)&O[(size_t)node * 128 + il * 8 + 4]      = make_float4(acc[4], acc[5], acc[6], acc[7]);
        *(float4*)&O[(size_t)node * 128 + 64 + il * 8]     = make_float4(acc[8], acc[9], acc[10], acc[11]);
        *(float4*)&O[(size_t)node * 128 + 64 + il * 8 + 4] = make_float4(acc[12], acc[13], acc[14], acc[15]);
    }
}

// ---------- launch ----------

extern "C" void kernel_launch(void* const* d_in, const int* in_sizes, int n_in,
                              void* d_out, int out_size, void* d_ws, size_t ws_size,
                              hipStream_t stream) {
    const float* x  = (const float*)d_in[0];
    const float* W1 = (const float*)d_in[1];
    const float* b1 = (const float*)d_in[2];
    const float* W2 = (const float*)d_in[3];
    const float* b2 = (const float*)d_in[4];
    const int*   ei = (const int*)d_in[5];

    const int N = in_sizes[0] / 128;
    const int E = in_sizes[5] / 2;
    const int* src = ei;
    const int* dst = ei + E;

    char* p = (char*)d_ws;
    ushort* gb    = (ushort*)p; p += (size_t)N * 128 * sizeof(ushort);   // bf16 g = dinv*h
    ushort* tb    = (ushort*)p; p += (size_t)N * 128 * sizeof(ushort);   // bf16 layer-1 activation
    int*    cnt   = (int*)p;    p += (size_t)N * sizeof(int);
    int*    cursor= (int*)p;    p += (size_t)N * sizeof(int);
    int*    off   = (int*)p;    p += (size_t)N * sizeof(int);
    float*  dinv  = (float*)p;  p += (size_t)N * sizeof(float);
    int*    srcs  = (int*)p;    p += (size_t)E * sizeof(int);
    ushort* Wt1   = (ushort*)p; p += 16384 * sizeof(ushort);
    ushort* Wt2   = (ushort*)p; p += 16384 * sizeof(ushort);
    int*    bsum  = (int*)p;    p += 1024;

    const int nb = (N + 1023) / 1024;
    const int nbt = (N + 63) / 64;

    zero_k <<<(N + NBLK - 1) / NBLK, NBLK, 0, stream>>>(cnt, N);
    count_k<<<(E + NBLK - 1) / NBLK, NBLK, 0, stream>>>(dst, E, cnt);
    scan1_k<<<nb, NBLK, 0, stream>>>(cnt, N, off, bsum);
    scan2_k<<<1, 128, 0, stream>>>(bsum, nb);
    scan3_k<<<(N + NBLK - 1) / NBLK, NBLK, 0, stream>>>(off, bsum, cnt, cursor, dinv, N);
    fill_k <<<(E + NBLK - 1) / NBLK, NBLK, 0, stream>>>(src, dst, E, cursor, srcs);
    wcast_k<<<128, NBLK, 0, stream>>>(W1, W2, Wt1, Wt2);

    const int agg_blocks = (N * 8 + NBLK - 1) / NBLK;   // 8 lanes/node

    gemm_mfma_k<1><<<512, NBLK, 0, stream>>>(x, Wt1, dinv, gb, N, nbt);
    aggregate_k<1><<<agg_blocks, NBLK, 0, stream>>>(gb, off, cnt, srcs, dinv, b1, tb, N, 1);
    gemm_mfma_k<0><<<512, NBLK, 0, stream>>>(tb, Wt2, dinv, gb, N, nbt);
    aggregate_k<0><<<agg_blocks, NBLK, 0, stream>>>(gb, off, cnt, srcs, dinv, b2, d_out, N, 0);
}

// Round 6
// 195.923 us; speedup vs baseline: 1.0582x; 1.0582x over previous
//
#include <hip/hip_runtime.h>
#include <math.h>

#define NBLK 256

typedef __attribute__((ext_vector_type(8))) short short8v;  // 8 bf16 (4 VGPR)
typedef __attribute__((ext_vector_type(4))) float f32x4;

__device__ __forceinline__ unsigned cvt_pk_bf16(float lo, float hi) {
    unsigned r;
    asm("v_cvt_pk_bf16_f32 %0, %1, %2" : "=v"(r) : "v"(lo), "v"(hi));
    return r;
}
__device__ __forceinline__ float bf_lo(unsigned u) { return __uint_as_float(u << 16); }
__device__ __forceinline__ float bf_hi(unsigned u) { return __uint_as_float(u & 0xffff0000u); }

__device__ __forceinline__ float fast_tanh(float x) {
    float cx = fminf(fmaxf(x, -15.f), 15.f);
    float e = __expf(2.f * cx);
    return (e - 1.f) / (e + 1.f);
}

// ---------- preprocessing: CSR by dst ----------

__global__ __launch_bounds__(NBLK) void zero_k(int* p, int n) {
    int i = blockIdx.x * blockDim.x + threadIdx.x;
    if (i < n) p[i] = 0;
}

__global__ __launch_bounds__(NBLK) void count_k(const int* __restrict__ dst, int E, int* __restrict__ cnt) {
    int e = blockIdx.x * blockDim.x + threadIdx.x;
    if (e < E) atomicAdd(&cnt[dst[e]], 1);
}

__global__ __launch_bounds__(NBLK) void scan1_k(const int* __restrict__ cnt, int n,
                                                int* __restrict__ off, int* __restrict__ bsum) {
    __shared__ int ls[NBLK];
    int base = blockIdx.x * 1024 + threadIdx.x * 4;
    int v[4]; int s = 0;
#pragma unroll
    for (int i = 0; i < 4; ++i) {
        int idx = base + i;
        v[i] = (idx < n) ? cnt[idx] : 0;
        s += v[i];
    }
    ls[threadIdx.x] = s;
    __syncthreads();
    for (int o = 1; o < NBLK; o <<= 1) {
        int t = (threadIdx.x >= (unsigned)o) ? ls[threadIdx.x - o] : 0;
        __syncthreads();
        ls[threadIdx.x] += t;
        __syncthreads();
    }
    int run = ls[threadIdx.x] - s;
#pragma unroll
    for (int i = 0; i < 4; ++i) {
        int idx = base + i;
        if (idx < n) off[idx] = run;
        run += v[i];
    }
    if (threadIdx.x == NBLK - 1) bsum[blockIdx.x] = ls[NBLK - 1];
}

__global__ void scan2_k(int* bsum, int nb) {
    __shared__ int ls[128];
    int t = threadIdx.x;
    int v = (t < nb) ? bsum[t] : 0;
    ls[t] = v;
    __syncthreads();
    for (int o = 1; o < 128; o <<= 1) {
        int tv = (t >= o) ? ls[t - o] : 0;
        __syncthreads();
        ls[t] += tv;
        __syncthreads();
    }
    if (t < nb) bsum[t] = ls[t] - v;
}

__global__ __launch_bounds__(NBLK) void scan3_k(int* __restrict__ off, const int* __restrict__ bsum,
                                                const int* __restrict__ cnt, int* __restrict__ cursor,
                                                float* __restrict__ dinv, int n) {
    int i = blockIdx.x * blockDim.x + threadIdx.x;
    if (i < n) {
        int o = off[i] + bsum[i >> 10];
        off[i] = o;
        cursor[i] = o;                           // fill cursor starts at bucket base
        dinv[i] = rsqrtf((float)(cnt[i] + 1));   // deg includes self-loop
    }
}

// fill: only src index needs to be scattered (norm folded into g rows).
__global__ __launch_bounds__(NBLK) void fill_k(const int* __restrict__ src, const int* __restrict__ dst, int E,
                                               int* __restrict__ cursor, int* __restrict__ srcs) {
    int e = blockIdx.x * blockDim.x + threadIdx.x;
    if (e >= E) return;
    int idx = atomicAdd(&cursor[dst[e]], 1);
    srcs[idx] = src[e];
}

// cast + transpose both weight matrices: Wt[col][k] bf16 (128x128 each)
__global__ __launch_bounds__(NBLK) void wcast_k(const float* __restrict__ W1, const float* __restrict__ W2,
                                                ushort* __restrict__ Wt1, ushort* __restrict__ Wt2) {
    int i = blockIdx.x * blockDim.x + threadIdx.x;   // 0..32767
    int which = i >> 14;
    int idx = i & 16383;
    const float* W = which ? W2 : W1;
    ushort* Wt = which ? Wt2 : Wt1;
    int k = idx >> 7, c = idx & 127;
    float v = W[idx];
    Wt[c * 128 + k] = (ushort)(cvt_pk_bf16(v, v) & 0xffffu);
}

// ---------- GEMM: Gb(bf16) = dinv[row] * (Xin @ W) via MFMA 16x16x32 bf16 ----------
// block 256 = 4 waves; one 64-row tile per block (grid = nbt, ~6 blocks/CU).
// W staged in LDS (32KB, XOR-swizzled 16B units: addr = col*16 + (ku ^ (col&15))) -> B ds_reads
// inside the MFMA loop (no register residency needed, VGPR <= 128, 4 waves/EU cap).
// X staged coalesced -> (cvt) -> XOR-swizzled LDS. LDS total 48KB -> 3 blocks/CU.
// A-frag: row = lane&15, k = (lane>>4)*8+j. B: col = lane&15. D: col = lane&15, row = (lane>>4)*4+reg.

template<int CVT>
__global__ __launch_bounds__(NBLK, 4) void gemm_mfma_k(const void* __restrict__ Xin,
                                                       const ushort* __restrict__ Wt,
                                                       const float* __restrict__ dinv,
                                                       ushort* __restrict__ Gb, int nrows) {
    __shared__ unsigned Xls[64 * 64];    // 16KB: 64 rows x 16 units(8 bf16), swizzled
    __shared__ unsigned Wls[128 * 64];   // 32KB: 128 cols x 16 units(8 bf16), swizzled
    const int t = threadIdx.x;
    const int lane = t & 63;
    const int wv = t >> 6;
    const int l15 = lane & 15;
    const int g = lane >> 4;
    const int row0 = blockIdx.x * 64;

    // stage W: 2048 uint4 units, linear global -> swizzled LDS
    {
        const uint4* Wv = (const uint4*)Wt;
        for (int i = t; i < 2048; i += NBLK) {
            int col = i >> 4, ku = i & 15;
            *(uint4*)&Wls[(col * 16 + (ku ^ (col & 15))) * 4] = Wv[i];
        }
    }
    // stage X tile: 64 rows x 16 units
    {
        int r = t >> 2;
        int rg = row0 + r;
#pragma unroll
        for (int j = 0; j < 4; ++j) {
            int u = (t & 3) + 4 * j;
            uint4 val;
            if (CVT) {
                float4 f0 = make_float4(0.f,0.f,0.f,0.f), f1 = f0;
                if (rg < nrows) {
                    const float4* Xv = (const float4*)Xin;
                    f0 = Xv[(size_t)rg * 32 + u * 2];
                    f1 = Xv[(size_t)rg * 32 + u * 2 + 1];
                }
                val.x = cvt_pk_bf16(f0.x, f0.y); val.y = cvt_pk_bf16(f0.z, f0.w);
                val.z = cvt_pk_bf16(f1.x, f1.y); val.w = cvt_pk_bf16(f1.z, f1.w);
            } else {
                val = make_uint4(0u,0u,0u,0u);
                if (rg < nrows) val = ((const uint4*)Xin)[(size_t)rg * 16 + u];
            }
            *(uint4*)&Xls[(r * 16 + (u ^ (r & 15))) * 4] = val;
        }
    }
    __syncthreads();

    short8v A[4];
#pragma unroll
    for (int ks = 0; ks < 4; ++ks) {
        int r = wv * 16 + l15;
        int u = ks * 4 + g;
        A[ks] = *(short8v*)&Xls[(r * 16 + (u ^ (r & 15))) * 4];
    }

    f32x4 acc[8];
#pragma unroll
    for (int nt = 0; nt < 8; ++nt) acc[nt] = (f32x4){0.f, 0.f, 0.f, 0.f};
#pragma unroll
    for (int nt = 0; nt < 8; ++nt) {
        int col = nt * 16 + l15;
#pragma unroll
        for (int ks = 0; ks < 4; ++ks) {
            int ku = ks * 4 + g;
            short8v b = *(short8v*)&Wls[(col * 16 + (ku ^ (col & 15))) * 4];
            acc[nt] = __builtin_amdgcn_mfma_f32_16x16x32_bf16(A[ks], b, acc[nt], 0, 0, 0);
        }
    }

    int trow0 = row0 + wv * 16;
    float dv[4];
#pragma unroll
    for (int q = 0; q < 4; ++q) {
        int row = trow0 + g * 4 + q;
        dv[q] = (row < nrows) ? dinv[row] : 0.f;
    }
#pragma unroll
    for (int nt = 0; nt < 8; ++nt)
#pragma unroll
        for (int q = 0; q < 4; ++q) {
            int row = trow0 + g * 4 + q;
            if (row < nrows) {
                float val = acc[nt][q] * dv[q];
                Gb[(size_t)row * 128 + nt * 16 + l15] =
                    (ushort)(cvt_pk_bf16(val, val) & 0xffffu);
            }
        }
}

// ---------- aggregate (bf16 gather, norm-free) ----------
// out[n] = dinv[n] * (g[n] + sum_{e: dst=n} g[src]) + b, opt tanh.
// 8 nodes/wave, 8 lanes/node; lane il owns uint4 units {il, il+8}.
// unroll x4 -> 8 b128 gathers in flight per lane; tail slots gather own row (L1-hot) weight 0.

#define UPK_FMA(u4, nm, A) { \
    A[0] = fmaf(bf_lo((u4).x), (nm), A[0]); A[1] = fmaf(bf_hi((u4).x), (nm), A[1]); \
    A[2] = fmaf(bf_lo((u4).y), (nm), A[2]); A[3] = fmaf(bf_hi((u4).y), (nm), A[3]); \
    A[4] = fmaf(bf_lo((u4).z), (nm), A[4]); A[5] = fmaf(bf_hi((u4).z), (nm), A[5]); \
    A[6] = fmaf(bf_lo((u4).w), (nm), A[6]); A[7] = fmaf(bf_hi((u4).w), (nm), A[7]); }

template<int OUT_BF16>
__global__ __launch_bounds__(NBLK) void aggregate_k(const ushort* __restrict__ Gb,
                                                    const int* __restrict__ off, const int* __restrict__ cnt,
                                                    const int* __restrict__ srcs,
                                                    const float* __restrict__ dinv, const float* __restrict__ bias,
                                                    void* __restrict__ outp, int n, int apply_tanh) {
    int node = (blockIdx.x * blockDim.x + threadIdx.x) >> 3;
    if (node >= n) return;
    int il = threadIdx.x & 7;

    const uint4* Gv = (const uint4*)Gb;   // 16 uint4 per row
    size_t rb = (size_t)node * 16;
    uint4 s0 = Gv[rb + il], s1 = Gv[rb + 8 + il];
    float acc[16] = {
        bf_lo(s0.x), bf_hi(s0.x), bf_lo(s0.y), bf_hi(s0.y),
        bf_lo(s0.z), bf_hi(s0.z), bf_lo(s0.w), bf_hi(s0.w),
        bf_lo(s1.x), bf_hi(s1.x), bf_lo(s1.y), bf_hi(s1.y),
        bf_lo(s1.z), bf_hi(s1.z), bf_lo(s1.w), bf_hi(s1.w)
    };

    int e0 = off[node];
    int deg = cnt[node];
    for (int b = 0; b < deg; b += 4) {
        int sidx[4]; float nm[4];
#pragma unroll
        for (int q = 0; q < 4; ++q) {
            bool v = (b + q) < deg;
            sidx[q] = v ? srcs[e0 + b + q] : node;   // invalid -> own row (L1-hot)
            nm[q] = v ? 1.f : 0.f;
        }
        uint4 g0[4], g1[4];
#pragma unroll
        for (int q = 0; q < 4; ++q) {
            size_t r = (size_t)sidx[q] * 16;
            g0[q] = Gv[r + il];
            g1[q] = Gv[r + 8 + il];
        }
#pragma unroll
        for (int q = 0; q < 4; ++q) {
            UPK_FMA(g0[q], nm[q], acc);
            UPK_FMA(g1[q], nm[q], (acc + 8));
        }
    }

    float dvn = dinv[node];
    float4 b0 = *(const float4*)&bias[il * 8];
    float4 b1 = *(const float4*)&bias[il * 8 + 4];
    float4 b2 = *(const float4*)&bias[64 + il * 8];
    float4 b3 = *(const float4*)&bias[64 + il * 8 + 4];
    acc[0]  = fmaf(acc[0],  dvn, b0.x); acc[1]  = fmaf(acc[1],  dvn, b0.y);
    acc[2]  = fmaf(acc[2],  dvn, b0.z); acc[3]  = fmaf(acc[3],  dvn, b0.w);
    acc[4]  = fmaf(acc[4],  dvn, b1.x); acc[5]  = fmaf(acc[5],  dvn, b1.y);
    acc[6]  = fmaf(acc[6],  dvn, b1.z); acc[7]  = fmaf(acc[7],  dvn, b1.w);
    acc[8]  = fmaf(acc[8],  dvn, b2.x); acc[9]  = fmaf(acc[9],  dvn, b2.y);
    acc[10] = fmaf(acc[10], dvn, b2.z); acc[11] = fmaf(acc[11], dvn, b2.w);
    acc[12] = fmaf(acc[12], dvn, b3.x); acc[13] = fmaf(acc[13], dvn, b3.y);
    acc[14] = fmaf(acc[14], dvn, b3.z); acc[15] = fmaf(acc[15], dvn, b3.w);

    if (apply_tanh) {
#pragma unroll
        for (int i = 0; i < 16; ++i) acc[i] = fast_tanh(acc[i]);
    }

    if (OUT_BF16) {
        uint4 o0, o1;
        o0.x = cvt_pk_bf16(acc[0],  acc[1]);  o0.y = cvt_pk_bf16(acc[2],  acc[3]);
        o0.z = cvt_pk_bf16(acc[4],  acc[5]);  o0.w = cvt_pk_bf16(acc[6],  acc[7]);
        o1.x = cvt_pk_bf16(acc[8],  acc[9]);  o1.y = cvt_pk_bf16(acc[10], acc[11]);
        o1.z = cvt_pk_bf16(acc[12], acc[13]); o1.w = cvt_pk_bf16(acc[14], acc[15]);
        uint4* O = (uint4*)outp;
        O[(size_t)node * 16 + il] = o0;
        O[(size_t)node * 16 + 8 + il] = o1;
    } else {
        float* O = (float*)outp;
        *(float4*)&O[(size_t)node * 128 + il * 8]          = make_float4(acc[0], acc[1], acc[2], acc[3]);
        *(float4*)&O[(size_t)node * 128 + il * 8 + 4]      = make_float4(acc[4], acc[5], acc[6], acc[7]);
        *(float4*)&O[(size_t)node * 128 + 64 + il * 8]     = make_float4(acc[8], acc[9], acc[10], acc[11]);
        *(float4*)&O[(size_t)node * 128 + 64 + il * 8 + 4] = make_float4(acc[12], acc[13], acc[14], acc[15]);
    }
}

// ---------- launch ----------

extern "C" void kernel_launch(void* const* d_in, const int* in_sizes, int n_in,
                              void* d_out, int out_size, void* d_ws, size_t ws_size,
                              hipStream_t stream) {
    const float* x  = (const float*)d_in[0];
    const float* W1 = (const float*)d_in[1];
    const float* b1 = (const float*)d_in[2];
    const float* W2 = (const float*)d_in[3];
    const float* b2 = (const float*)d_in[4];
    const int*   ei = (const int*)d_in[5];

    const int N = in_sizes[0] / 128;
    const int E = in_sizes[5] / 2;
    const int* src = ei;
    const int* dst = ei + E;

    char* p = (char*)d_ws;
    ushort* gb    = (ushort*)p; p += (size_t)N * 128 * sizeof(ushort);   // bf16 g = dinv*h
    ushort* tb    = (ushort*)p; p += (size_t)N * 128 * sizeof(ushort);   // bf16 layer-1 activation
    int*    cnt   = (int*)p;    p += (size_t)N * sizeof(int);
    int*    cursor= (int*)p;    p += (size_t)N * sizeof(int);
    int*    off   = (int*)p;    p += (size_t)N * sizeof(int);
    float*  dinv  = (float*)p;  p += (size_t)N * sizeof(float);
    int*    srcs  = (int*)p;    p += (size_t)E * sizeof(int);
    ushort* Wt1   = (ushort*)p; p += 16384 * sizeof(ushort);
    ushort* Wt2   = (ushort*)p; p += 16384 * sizeof(ushort);
    int*    bsum  = (int*)p;    p += 1024;

    const int nb = (N + 1023) / 1024;
    const int nbt = (N + 63) / 64;

    zero_k <<<(N + NBLK - 1) / NBLK, NBLK, 0, stream>>>(cnt, N);
    count_k<<<(E + NBLK - 1) / NBLK, NBLK, 0, stream>>>(dst, E, cnt);
    scan1_k<<<nb, NBLK, 0, stream>>>(cnt, N, off, bsum);
    scan2_k<<<1, 128, 0, stream>>>(bsum, nb);
    scan3_k<<<(N + NBLK - 1) / NBLK, NBLK, 0, stream>>>(off, bsum, cnt, cursor, dinv, N);
    fill_k <<<(E + NBLK - 1) / NBLK, NBLK, 0, stream>>>(src, dst, E, cursor, srcs);
    wcast_k<<<128, NBLK, 0, stream>>>(W1, W2, Wt1, Wt2);

    const int agg_blocks = (N * 8 + NBLK - 1) / NBLK;   // 8 lanes/node

    gemm_mfma_k<1><<<nbt, NBLK, 0, stream>>>(x, Wt1, dinv, gb, N);
    aggregate_k<1><<<agg_blocks, NBLK, 0, stream>>>(gb, off, cnt, srcs, dinv, b1, tb, N, 1);
    gemm_mfma_k<0><<<nbt, NBLK, 0, stream>>>(tb, Wt2, dinv, gb, N);
    aggregate_k<0><<<agg_blocks, NBLK, 0, stream>>>(gb, off, cnt, srcs, dinv, b2, d_out, N, 0);
}

// Round 7
// 168.422 us; speedup vs baseline: 1.2310x; 1.1633x over previous
//
#include <hip/hip_runtime.h>
#include <math.h>

#define NBLK 256

typedef __attribute__((ext_vector_type(8))) short short8v;  // 8 bf16 (4 VGPR)
typedef __attribute__((ext_vector_type(4))) float f32x4;

__device__ __forceinline__ unsigned cvt_pk_bf16(float lo, float hi) {
    unsigned r;
    asm("v_cvt_pk_bf16_f32 %0, %1, %2" : "=v"(r) : "v"(lo), "v"(hi));
    return r;
}
__device__ __forceinline__ float bf_lo(unsigned u) { return __uint_as_float(u << 16); }
__device__ __forceinline__ float bf_hi(unsigned u) { return __uint_as_float(u & 0xffff0000u); }

__device__ __forceinline__ float fast_tanh(float x) {
    float cx = fminf(fmaxf(x, -15.f), 15.f);
    float e = __expf(2.f * cx);
    return (e - 1.f) / (e + 1.f);
}

// ---------- scan (exclusive prefix over cnt -> off) ----------

__global__ __launch_bounds__(NBLK) void scan1_k(const int* __restrict__ cnt, int n,
                                                int* __restrict__ off, int* __restrict__ bsum) {
    __shared__ int ls[NBLK];
    int base = blockIdx.x * 1024 + threadIdx.x * 4;
    int v[4]; int s = 0;
#pragma unroll
    for (int i = 0; i < 4; ++i) {
        int idx = base + i;
        v[i] = (idx < n) ? cnt[idx] : 0;
        s += v[i];
    }
    ls[threadIdx.x] = s;
    __syncthreads();
    for (int o = 1; o < NBLK; o <<= 1) {
        int t = (threadIdx.x >= (unsigned)o) ? ls[threadIdx.x - o] : 0;
        __syncthreads();
        ls[threadIdx.x] += t;
        __syncthreads();
    }
    int run = ls[threadIdx.x] - s;
#pragma unroll
    for (int i = 0; i < 4; ++i) {
        int idx = base + i;
        if (idx < n) off[idx] = run;
        run += v[i];
    }
    if (threadIdx.x == NBLK - 1) bsum[blockIdx.x] = ls[NBLK - 1];
}

__global__ void scan2_k(int* bsum, int nb) {
    __shared__ int ls[128];
    int t = threadIdx.x;
    int v = (t < nb) ? bsum[t] : 0;
    ls[t] = v;
    __syncthreads();
    for (int o = 1; o < 128; o <<= 1) {
        int tv = (t >= o) ? ls[t - o] : 0;
        __syncthreads();
        ls[t] += tv;
        __syncthreads();
    }
    if (t < nb) bsum[t] = ls[t] - v;
}

__global__ __launch_bounds__(NBLK) void scan3_k(int* __restrict__ off, const int* __restrict__ bsum,
                                                const int* __restrict__ cnt,
                                                float* __restrict__ dinv, int n) {
    int i = blockIdx.x * blockDim.x + threadIdx.x;
    if (i < n) {
        off[i] += bsum[i >> 10];
        dinv[i] = rsqrtf((float)(cnt[i] + 1));   // deg includes self-loop
    }
}

// atomic-free fill: position was recorded during the fused count pass.
__global__ __launch_bounds__(NBLK) void fill2_k(const int* __restrict__ src, const int* __restrict__ dst, int E,
                                                const int* __restrict__ off, const int* __restrict__ pos,
                                                int* __restrict__ srcs) {
    int e = blockIdx.x * blockDim.x + threadIdx.x;
    if (e >= E) return;
    srcs[off[dst[e]] + pos[e]] = src[e];
}

// cast + transpose both weight matrices: Wt[col][k] bf16 (128x128 each)
__global__ __launch_bounds__(NBLK) void wcast_k(const float* __restrict__ W1, const float* __restrict__ W2,
                                                ushort* __restrict__ Wt1, ushort* __restrict__ Wt2) {
    int i = blockIdx.x * blockDim.x + threadIdx.x;   // 0..32767
    int which = i >> 14;
    int idx = i & 16383;
    const float* W = which ? W2 : W1;
    ushort* Wt = which ? Wt2 : Wt1;
    int k = idx >> 7, c = idx & 127;
    float v = W[idx];
    Wt[c * 128 + k] = (ushort)(cvt_pk_bf16(v, v) & 0xffffu);
}

// ---------- GEMM: Gb(bf16) = [dinv[row] *] (Xin @ W) via MFMA 16x16x32 bf16 ----------
// block 256 = 4 waves; one 64-row tile per block. W + X staged in XOR-swizzled LDS (48KB).
// DO_COUNT: grid-stride degree-count pass (pos[e] = atomicAdd(cnt[dst[e]],1)) fused at the end,
// hidden under other blocks' MFMA/staging (gemm1 does not need dinv -> independent of CSR).

template<int CVT, int DINV, int DO_COUNT>
__global__ __launch_bounds__(NBLK, 4) void gemm_mfma_k(const void* __restrict__ Xin,
                                                       const ushort* __restrict__ Wt,
                                                       const float* __restrict__ dinv,
                                                       ushort* __restrict__ Gb, int nrows,
                                                       const int* __restrict__ dste,
                                                       int* __restrict__ cntp,
                                                       int* __restrict__ posp, int E) {
    __shared__ unsigned Xls[64 * 64];    // 16KB: 64 rows x 16 units(8 bf16), swizzled
    __shared__ unsigned Wls[128 * 64];   // 32KB: 128 cols x 16 units(8 bf16), swizzled
    const int t = threadIdx.x;
    const int lane = t & 63;
    const int wv = t >> 6;
    const int l15 = lane & 15;
    const int g = lane >> 4;
    const int row0 = blockIdx.x * 64;

    // stage W: 2048 uint4 units, linear global -> swizzled LDS
    {
        const uint4* Wv = (const uint4*)Wt;
        for (int i = t; i < 2048; i += NBLK) {
            int col = i >> 4, ku = i & 15;
            *(uint4*)&Wls[(col * 16 + (ku ^ (col & 15))) * 4] = Wv[i];
        }
    }
    // stage X tile: 64 rows x 16 units
    {
        int r = t >> 2;
        int rg = row0 + r;
#pragma unroll
        for (int j = 0; j < 4; ++j) {
            int u = (t & 3) + 4 * j;
            uint4 val;
            if (CVT) {
                float4 f0 = make_float4(0.f,0.f,0.f,0.f), f1 = f0;
                if (rg < nrows) {
                    const float4* Xv = (const float4*)Xin;
                    f0 = Xv[(size_t)rg * 32 + u * 2];
                    f1 = Xv[(size_t)rg * 32 + u * 2 + 1];
                }
                val.x = cvt_pk_bf16(f0.x, f0.y); val.y = cvt_pk_bf16(f0.z, f0.w);
                val.z = cvt_pk_bf16(f1.x, f1.y); val.w = cvt_pk_bf16(f1.z, f1.w);
            } else {
                val = make_uint4(0u,0u,0u,0u);
                if (rg < nrows) val = ((const uint4*)Xin)[(size_t)rg * 16 + u];
            }
            *(uint4*)&Xls[(r * 16 + (u ^ (r & 15))) * 4] = val;
        }
    }
    __syncthreads();

    short8v A[4];
#pragma unroll
    for (int ks = 0; ks < 4; ++ks) {
        int r = wv * 16 + l15;
        int u = ks * 4 + g;
        A[ks] = *(short8v*)&Xls[(r * 16 + (u ^ (r & 15))) * 4];
    }

    f32x4 acc[8];
#pragma unroll
    for (int nt = 0; nt < 8; ++nt) acc[nt] = (f32x4){0.f, 0.f, 0.f, 0.f};
#pragma unroll
    for (int nt = 0; nt < 8; ++nt) {
        int col = nt * 16 + l15;
#pragma unroll
        for (int ks = 0; ks < 4; ++ks) {
            int ku = ks * 4 + g;
            short8v b = *(short8v*)&Wls[(col * 16 + (ku ^ (col & 15))) * 4];
            acc[nt] = __builtin_amdgcn_mfma_f32_16x16x32_bf16(A[ks], b, acc[nt], 0, 0, 0);
        }
    }

    int trow0 = row0 + wv * 16;
    float dv[4];
#pragma unroll
    for (int q = 0; q < 4; ++q) {
        int row = trow0 + g * 4 + q;
        dv[q] = DINV ? ((row < nrows) ? dinv[row] : 0.f) : 1.f;
    }
#pragma unroll
    for (int nt = 0; nt < 8; ++nt)
#pragma unroll
        for (int q = 0; q < 4; ++q) {
            int row = trow0 + g * 4 + q;
            if (row < nrows) {
                float val = DINV ? acc[nt][q] * dv[q] : acc[nt][q];
                Gb[(size_t)row * 128 + nt * 16 + l15] =
                    (ushort)(cvt_pk_bf16(val, val) & 0xffffu);
            }
        }

    if (DO_COUNT) {
        int stride = gridDim.x * NBLK;
        for (int e = blockIdx.x * NBLK + t; e < E; e += stride)
            posp[e] = atomicAdd(&cntp[dste[e]], 1);
    }
}

// ---------- aggregate (bf16 gather) ----------
// out[n] = dinv[n] * ( w_self*g[n] + sum_{e: dst=n} w_e*g[src] ) + b, opt tanh.
// SRC_DINV: w = dinv[src] (layer 1: g rows unscaled); else w = 1 (g rows prescaled).
// 4 nodes/wave, 16 lanes/node; lane il owns uint4 unit il -> one full 256B row per instruction.
// unroll x8 -> 8 rows in flight; tail slots gather own row (L1-hot) with weight 0.

#define UPK_FMA(u4, nm, A) { \
    A[0] = fmaf(bf_lo((u4).x), (nm), A[0]); A[1] = fmaf(bf_hi((u4).x), (nm), A[1]); \
    A[2] = fmaf(bf_lo((u4).y), (nm), A[2]); A[3] = fmaf(bf_hi((u4).y), (nm), A[3]); \
    A[4] = fmaf(bf_lo((u4).z), (nm), A[4]); A[5] = fmaf(bf_hi((u4).z), (nm), A[5]); \
    A[6] = fmaf(bf_lo((u4).w), (nm), A[6]); A[7] = fmaf(bf_hi((u4).w), (nm), A[7]); }

template<int SRC_DINV, int TANH_, int OUT_BF16>
__global__ __launch_bounds__(NBLK, 4) void aggregate_k(const ushort* __restrict__ Gb,
                                                       const int* __restrict__ off, const int* __restrict__ cnt,
                                                       const int* __restrict__ srcs,
                                                       const float* __restrict__ dinv,
                                                       const float* __restrict__ bias,
                                                       void* __restrict__ outp, int n) {
    int node = (blockIdx.x * blockDim.x + threadIdx.x) >> 4;
    if (node >= n) return;
    int il = threadIdx.x & 15;

    const uint4* Gv = (const uint4*)Gb;   // 16 uint4 per row
    float dvn = dinv[node];
    float sw = SRC_DINV ? dvn : 1.f;
    uint4 s0 = Gv[(size_t)node * 16 + il];
    float acc[8] = {
        bf_lo(s0.x) * sw, bf_hi(s0.x) * sw, bf_lo(s0.y) * sw, bf_hi(s0.y) * sw,
        bf_lo(s0.z) * sw, bf_hi(s0.z) * sw, bf_lo(s0.w) * sw, bf_hi(s0.w) * sw
    };

    int e0 = off[node];
    int deg = cnt[node];
    for (int b = 0; b < deg; b += 8) {
        int sidx[8]; float nm[8];
#pragma unroll
        for (int q = 0; q < 8; ++q) {
            bool v = (b + q) < deg;
            sidx[q] = v ? srcs[e0 + b + q] : node;   // invalid -> own row (L1-hot)
            nm[q] = v ? 1.f : 0.f;
        }
        if (SRC_DINV) {
#pragma unroll
            for (int q = 0; q < 8; ++q) nm[q] *= dinv[sidx[q]];   // 400KB table, L2-resident
        }
        uint4 gr[8];
#pragma unroll
        for (int q = 0; q < 8; ++q) gr[q] = Gv[(size_t)sidx[q] * 16 + il];
#pragma unroll
        for (int q = 0; q < 8; ++q) UPK_FMA(gr[q], nm[q], acc);
    }

    float4 b0 = *(const float4*)&bias[il * 8];
    float4 b1 = *(const float4*)&bias[il * 8 + 4];
    float r[8];
    r[0] = fmaf(acc[0], dvn, b0.x); r[1] = fmaf(acc[1], dvn, b0.y);
    r[2] = fmaf(acc[2], dvn, b0.z); r[3] = fmaf(acc[3], dvn, b0.w);
    r[4] = fmaf(acc[4], dvn, b1.x); r[5] = fmaf(acc[5], dvn, b1.y);
    r[6] = fmaf(acc[6], dvn, b1.z); r[7] = fmaf(acc[7], dvn, b1.w);

    if (TANH_) {
#pragma unroll
        for (int i = 0; i < 8; ++i) r[i] = fast_tanh(r[i]);
    }

    if (OUT_BF16) {
        uint4 o;
        o.x = cvt_pk_bf16(r[0], r[1]); o.y = cvt_pk_bf16(r[2], r[3]);
        o.z = cvt_pk_bf16(r[4], r[5]); o.w = cvt_pk_bf16(r[6], r[7]);
        ((uint4*)outp)[(size_t)node * 16 + il] = o;
    } else {
        float* O = (float*)outp;
        *(float4*)&O[(size_t)node * 128 + il * 8]     = make_float4(r[0], r[1], r[2], r[3]);
        *(float4*)&O[(size_t)node * 128 + il * 8 + 4] = make_float4(r[4], r[5], r[6], r[7]);
    }
}

// ---------- launch ----------

extern "C" void kernel_launch(void* const* d_in, const int* in_sizes, int n_in,
                              void* d_out, int out_size, void* d_ws, size_t ws_size,
                              hipStream_t stream) {
    const float* x  = (const float*)d_in[0];
    const float* W1 = (const float*)d_in[1];
    const float* b1 = (const float*)d_in[2];
    const float* W2 = (const float*)d_in[3];
    const float* b2 = (const float*)d_in[4];
    const int*   ei = (const int*)d_in[5];

    const int N = in_sizes[0] / 128;
    const int E = in_sizes[5] / 2;
    const int* src = ei;
    const int* dst = ei + E;

    char* p = (char*)d_ws;
    ushort* gb    = (ushort*)p; p += (size_t)N * 128 * sizeof(ushort);   // bf16 h (layer1) / g2 (layer2)
    ushort* tb    = (ushort*)p; p += (size_t)N * 128 * sizeof(ushort);   // bf16 layer-1 activation
    int*    cnt   = (int*)p;    p += (size_t)N * sizeof(int);
    int*    off   = (int*)p;    p += (size_t)N * sizeof(int);
    float*  dinv  = (float*)p;  p += (size_t)N * sizeof(float);
    int*    srcs  = (int*)p;    p += (size_t)E * sizeof(int);
    int*    pos   = (int*)p;    p += (size_t)E * sizeof(int);
    ushort* Wt1   = (ushort*)p; p += 16384 * sizeof(ushort);
    ushort* Wt2   = (ushort*)p; p += 16384 * sizeof(ushort);
    int*    bsum  = (int*)p;    p += 1024;

    const int nb  = (N + 1023) / 1024;
    const int nbt = (N + 63) / 64;
    const int agg_blocks = ((size_t)N * 16 + NBLK - 1) / NBLK;   // 16 lanes/node

    hipMemsetAsync(cnt, 0, (size_t)N * sizeof(int), stream);
    wcast_k<<<128, NBLK, 0, stream>>>(W1, W2, Wt1, Wt2);

    // layer-1 GEMM (no dinv needed) + fused degree count
    gemm_mfma_k<1, 0, 1><<<nbt, NBLK, 0, stream>>>(x, Wt1, nullptr, gb, N, dst, cnt, pos, E);

    scan1_k<<<nb, NBLK, 0, stream>>>(cnt, N, off, bsum);
    scan2_k<<<1, 128, 0, stream>>>(bsum, nb);
    scan3_k<<<(N + NBLK - 1) / NBLK, NBLK, 0, stream>>>(off, bsum, cnt, dinv, N);
    fill2_k<<<(E + NBLK - 1) / NBLK, NBLK, 0, stream>>>(src, dst, E, off, pos, srcs);

    // layer-1 aggregate: per-src dinv, tanh, bf16 out
    aggregate_k<1, 1, 1><<<agg_blocks, NBLK, 0, stream>>>(gb, off, cnt, srcs, dinv, b1, tb, N);
    // layer-2 GEMM: g2 = dinv * (tb @ W2)
    gemm_mfma_k<0, 1, 0><<<nbt, NBLK, 0, stream>>>(tb, Wt2, dinv, gb, N, nullptr, nullptr, nullptr, 0);
    // layer-2 aggregate: prescaled rows, f32 out
    aggregate_k<0, 0, 0><<<agg_blocks, NBLK, 0, stream>>>(gb, off, cnt, srcs, dinv, b2, d_out, N);
}

// Round 8
// 165.958 us; speedup vs baseline: 1.2493x; 1.0148x over previous
//
#include <hip/hip_runtime.h>
#include <math.h>

#define NBLK 256

typedef __attribute__((ext_vector_type(8))) short short8v;  // 8 bf16 (4 VGPR)
typedef __attribute__((ext_vector_type(4))) float f32x4;

__device__ __forceinline__ unsigned cvt_pk_bf16(float lo, float hi) {
    unsigned r;
    asm("v_cvt_pk_bf16_f32 %0, %1, %2" : "=v"(r) : "v"(lo), "v"(hi));
    return r;
}
__device__ __forceinline__ float bf_lo(unsigned u) { return __uint_as_float(u << 16); }
__device__ __forceinline__ float bf_hi(unsigned u) { return __uint_as_float(u & 0xffff0000u); }

__device__ __forceinline__ float fast_tanh(float x) {
    float cx = fminf(fmaxf(x, -15.f), 15.f);
    float e = __expf(2.f * cx);
    return (e - 1.f) / (e + 1.f);
}

// ---------- scan: off = exclusive prefix of deg, deg[i] = sum_x cnt8[x][i] ----------

__global__ __launch_bounds__(NBLK) void scan1_k(const int* __restrict__ cnt8, int n,
                                                int* __restrict__ off, int* __restrict__ bsum) {
    __shared__ int ls[NBLK];
    int base = blockIdx.x * 1024 + threadIdx.x * 4;
    int v[4]; int s = 0;
#pragma unroll
    for (int i = 0; i < 4; ++i) {
        int idx = base + i;
        int d = 0;
        if (idx < n) {
#pragma unroll
            for (int x = 0; x < 8; ++x) d += cnt8[(size_t)x * n + idx];
        }
        v[i] = d;
        s += d;
    }
    ls[threadIdx.x] = s;
    __syncthreads();
    for (int o = 1; o < NBLK; o <<= 1) {
        int t = (threadIdx.x >= (unsigned)o) ? ls[threadIdx.x - o] : 0;
        __syncthreads();
        ls[threadIdx.x] += t;
        __syncthreads();
    }
    int run = ls[threadIdx.x] - s;
#pragma unroll
    for (int i = 0; i < 4; ++i) {
        int idx = base + i;
        if (idx < n) off[idx] = run;
        run += v[i];
    }
    if (threadIdx.x == NBLK - 1) bsum[blockIdx.x] = ls[NBLK - 1];
}

__global__ void scan2_k(int* bsum, int nb) {
    __shared__ int ls[128];
    int t = threadIdx.x;
    int v = (t < nb) ? bsum[t] : 0;
    ls[t] = v;
    __syncthreads();
    for (int o = 1; o < 128; o <<= 1) {
        int tv = (t >= o) ? ls[t - o] : 0;
        __syncthreads();
        ls[t] += tv;
        __syncthreads();
    }
    if (t < nb) bsum[t] = ls[t] - v;
}

// finalize off; transform cnt8 IN-PLACE into per-part bases base8[x][i] = off[i] + prefix_x;
// emit deg + dinv.
__global__ __launch_bounds__(NBLK) void scan3_k(int* __restrict__ off, const int* __restrict__ bsum,
                                                int* __restrict__ cnt8, int* __restrict__ deg,
                                                float* __restrict__ dinv, int n) {
    int i = blockIdx.x * blockDim.x + threadIdx.x;
    if (i < n) {
        int o = off[i] + bsum[i >> 10];
        off[i] = o;
        int run = o;
#pragma unroll
        for (int x = 0; x < 8; ++x) {
            size_t idx = (size_t)x * n + i;
            int c = cnt8[idx];
            cnt8[idx] = run;   // becomes base8
            run += c;
        }
        int d = run - o;
        deg[i] = d;
        dinv[i] = rsqrtf((float)(d + 1));   // deg includes self-loop
    }
}

// atomic-free fill: pos[e] = (p<<3)|part recorded during the fused count pass.
__global__ __launch_bounds__(NBLK) void fill2_k(const int* __restrict__ src, const int* __restrict__ dst, int E,
                                                const int* __restrict__ base8, const int* __restrict__ pos,
                                                int* __restrict__ srcs, int n) {
    int e = blockIdx.x * blockDim.x + threadIdx.x;
    if (e >= E) return;
    int pe = pos[e];
    srcs[base8[(size_t)(pe & 7) * n + dst[e]] + (pe >> 3)] = src[e];
}

// cast + transpose both weight matrices: Wt[col][k] bf16 (128x128 each)
__global__ __launch_bounds__(NBLK) void wcast_k(const float* __restrict__ W1, const float* __restrict__ W2,
                                                ushort* __restrict__ Wt1, ushort* __restrict__ Wt2) {
    int i = blockIdx.x * blockDim.x + threadIdx.x;   // 0..32767
    int which = i >> 14;
    int idx = i & 16383;
    const float* W = which ? W2 : W1;
    ushort* Wt = which ? Wt2 : Wt1;
    int k = idx >> 7, c = idx & 127;
    float v = W[idx];
    Wt[c * 128 + k] = (ushort)(cvt_pk_bf16(v, v) & 0xffffu);
}

// ---------- GEMM: Gb(bf16) = [dinv[row] *] (Xin @ W) via MFMA 16x16x32 bf16 ----------
// block 256 = 4 waves; one 64-row tile per block. W + X staged in XOR-swizzled LDS (48KB).
// DO_COUNT: grid-stride degree-count tail with XCD-LOCAL atomics — partition by blockIdx&7
// (round-robin block->XCD heuristic) so each cnt8 slice stays in one XCD's L2 (no cross-XCD
// line ping-pong). pos[e] = (p<<3)|part.

template<int CVT, int DINV, int DO_COUNT>
__global__ __launch_bounds__(NBLK, 4) void gemm_mfma_k(const void* __restrict__ Xin,
                                                       const ushort* __restrict__ Wt,
                                                       const float* __restrict__ dinv,
                                                       ushort* __restrict__ Gb, int nrows,
                                                       const int* __restrict__ dste,
                                                       int* __restrict__ cnt8,
                                                       int* __restrict__ posp, int E) {
    __shared__ unsigned Xls[64 * 64];    // 16KB: 64 rows x 16 units(8 bf16), swizzled
    __shared__ unsigned Wls[128 * 64];   // 32KB: 128 cols x 16 units(8 bf16), swizzled
    const int t = threadIdx.x;
    const int lane = t & 63;
    const int wv = t >> 6;
    const int l15 = lane & 15;
    const int g = lane >> 4;
    const int row0 = blockIdx.x * 64;

    // stage W: 2048 uint4 units, linear global -> swizzled LDS
    {
        const uint4* Wv = (const uint4*)Wt;
        for (int i = t; i < 2048; i += NBLK) {
            int col = i >> 4, ku = i & 15;
            *(uint4*)&Wls[(col * 16 + (ku ^ (col & 15))) * 4] = Wv[i];
        }
    }
    // stage X tile: 64 rows x 16 units
    {
        int r = t >> 2;
        int rg = row0 + r;
#pragma unroll
        for (int j = 0; j < 4; ++j) {
            int u = (t & 3) + 4 * j;
            uint4 val;
            if (CVT) {
                float4 f0 = make_float4(0.f,0.f,0.f,0.f), f1 = f0;
                if (rg < nrows) {
                    const float4* Xv = (const float4*)Xin;
                    f0 = Xv[(size_t)rg * 32 + u * 2];
                    f1 = Xv[(size_t)rg * 32 + u * 2 + 1];
                }
                val.x = cvt_pk_bf16(f0.x, f0.y); val.y = cvt_pk_bf16(f0.z, f0.w);
                val.z = cvt_pk_bf16(f1.x, f1.y); val.w = cvt_pk_bf16(f1.z, f1.w);
            } else {
                val = make_uint4(0u,0u,0u,0u);
                if (rg < nrows) val = ((const uint4*)Xin)[(size_t)rg * 16 + u];
            }
            *(uint4*)&Xls[(r * 16 + (u ^ (r & 15))) * 4] = val;
        }
    }
    __syncthreads();

    short8v A[4];
#pragma unroll
    for (int ks = 0; ks < 4; ++ks) {
        int r = wv * 16 + l15;
        int u = ks * 4 + g;
        A[ks] = *(short8v*)&Xls[(r * 16 + (u ^ (r & 15))) * 4];
    }

    f32x4 acc[8];
#pragma unroll
    for (int nt = 0; nt < 8; ++nt) acc[nt] = (f32x4){0.f, 0.f, 0.f, 0.f};
#pragma unroll
    for (int nt = 0; nt < 8; ++nt) {
        int col = nt * 16 + l15;
#pragma unroll
        for (int ks = 0; ks < 4; ++ks) {
            int ku = ks * 4 + g;
            short8v b = *(short8v*)&Wls[(col * 16 + (ku ^ (col & 15))) * 4];
            acc[nt] = __builtin_amdgcn_mfma_f32_16x16x32_bf16(A[ks], b, acc[nt], 0, 0, 0);
        }
    }

    int trow0 = row0 + wv * 16;
    float dv[4];
#pragma unroll
    for (int q = 0; q < 4; ++q) {
        int row = trow0 + g * 4 + q;
        dv[q] = DINV ? ((row < nrows) ? dinv[row] : 0.f) : 1.f;
    }
#pragma unroll
    for (int nt = 0; nt < 8; ++nt)
#pragma unroll
        for (int q = 0; q < 4; ++q) {
            int row = trow0 + g * 4 + q;
            if (row < nrows) {
                float val = DINV ? acc[nt][q] * dv[q] : acc[nt][q];
                Gb[(size_t)row * 128 + nt * 16 + l15] =
                    (ushort)(cvt_pk_bf16(val, val) & 0xffffu);
            }
        }

    if (DO_COUNT) {
        const int part = blockIdx.x & 7;
        int* cslice = cnt8 + (size_t)part * nrows;
        int stride = gridDim.x * NBLK;
        for (int e = blockIdx.x * NBLK + t; e < E; e += stride)
            posp[e] = (atomicAdd(&cslice[dste[e]], 1) << 3) | part;
    }
}

// ---------- aggregate (bf16 gather) ----------
// out[n] = dinv[n] * ( w_self*g[n] + sum_{e: dst=n} w_e*g[src] ) + b, opt tanh.
// SRC_DINV: w = dinv[src] (layer 1: g rows unscaled); else w = 1 (g rows prescaled).
// 4 nodes/wave, 16 lanes/node; lane il owns uint4 unit il -> one full 256B row per instruction.
// unroll x8 -> 8 rows in flight; tail slots gather own row (L1-hot) with weight 0.

#define UPK_FMA(u4, nm, A) { \
    A[0] = fmaf(bf_lo((u4).x), (nm), A[0]); A[1] = fmaf(bf_hi((u4).x), (nm), A[1]); \
    A[2] = fmaf(bf_lo((u4).y), (nm), A[2]); A[3] = fmaf(bf_hi((u4).y), (nm), A[3]); \
    A[4] = fmaf(bf_lo((u4).z), (nm), A[4]); A[5] = fmaf(bf_hi((u4).z), (nm), A[5]); \
    A[6] = fmaf(bf_lo((u4).w), (nm), A[6]); A[7] = fmaf(bf_hi((u4).w), (nm), A[7]); }

template<int SRC_DINV, int TANH_, int OUT_BF16>
__global__ __launch_bounds__(NBLK, 4) void aggregate_k(const ushort* __restrict__ Gb,
                                                       const int* __restrict__ off, const int* __restrict__ deg_,
                                                       const int* __restrict__ srcs,
                                                       const float* __restrict__ dinv,
                                                       const float* __restrict__ bias,
                                                       void* __restrict__ outp, int n) {
    int node = (blockIdx.x * blockDim.x + threadIdx.x) >> 4;
    if (node >= n) return;
    int il = threadIdx.x & 15;

    const uint4* Gv = (const uint4*)Gb;   // 16 uint4 per row
    float dvn = dinv[node];
    float sw = SRC_DINV ? dvn : 1.f;
    uint4 s0 = Gv[(size_t)node * 16 + il];
    float acc[8] = {
        bf_lo(s0.x) * sw, bf_hi(s0.x) * sw, bf_lo(s0.y) * sw, bf_hi(s0.y) * sw,
        bf_lo(s0.z) * sw, bf_hi(s0.z) * sw, bf_lo(s0.w) * sw, bf_hi(s0.w) * sw
    };

    int e0 = off[node];
    int deg = deg_[node];
    for (int b = 0; b < deg; b += 8) {
        int sidx[8]; float nm[8];
#pragma unroll
        for (int q = 0; q < 8; ++q) {
            bool v = (b + q) < deg;
            sidx[q] = v ? srcs[e0 + b + q] : node;   // invalid -> own row (L1-hot)
            nm[q] = v ? 1.f : 0.f;
        }
        if (SRC_DINV) {
#pragma unroll
            for (int q = 0; q < 8; ++q) nm[q] *= dinv[sidx[q]];   // 400KB table, L2-resident
        }
        uint4 gr[8];
#pragma unroll
        for (int q = 0; q < 8; ++q) gr[q] = Gv[(size_t)sidx[q] * 16 + il];
#pragma unroll
        for (int q = 0; q < 8; ++q) UPK_FMA(gr[q], nm[q], acc);
    }

    float4 b0 = *(const float4*)&bias[il * 8];
    float4 b1 = *(const float4*)&bias[il * 8 + 4];
    float r[8];
    r[0] = fmaf(acc[0], dvn, b0.x); r[1] = fmaf(acc[1], dvn, b0.y);
    r[2] = fmaf(acc[2], dvn, b0.z); r[3] = fmaf(acc[3], dvn, b0.w);
    r[4] = fmaf(acc[4], dvn, b1.x); r[5] = fmaf(acc[5], dvn, b1.y);
    r[6] = fmaf(acc[6], dvn, b1.z); r[7] = fmaf(acc[7], dvn, b1.w);

    if (TANH_) {
#pragma unroll
        for (int i = 0; i < 8; ++i) r[i] = fast_tanh(r[i]);
    }

    if (OUT_BF16) {
        uint4 o;
        o.x = cvt_pk_bf16(r[0], r[1]); o.y = cvt_pk_bf16(r[2], r[3]);
        o.z = cvt_pk_bf16(r[4], r[5]); o.w = cvt_pk_bf16(r[6], r[7]);
        ((uint4*)outp)[(size_t)node * 16 + il] = o;
    } else {
        float* O = (float*)outp;
        *(float4*)&O[(size_t)node * 128 + il * 8]     = make_float4(r[0], r[1], r[2], r[3]);
        *(float4*)&O[(size_t)node * 128 + il * 8 + 4] = make_float4(r[4], r[5], r[6], r[7]);
    }
}

// ---------- launch ----------

extern "C" void kernel_launch(void* const* d_in, const int* in_sizes, int n_in,
                              void* d_out, int out_size, void* d_ws, size_t ws_size,
                              hipStream_t stream) {
    const float* x  = (const float*)d_in[0];
    const float* W1 = (const float*)d_in[1];
    const float* b1 = (const float*)d_in[2];
    const float* W2 = (const float*)d_in[3];
    const float* b2 = (const float*)d_in[4];
    const int*   ei = (const int*)d_in[5];

    const int N = in_sizes[0] / 128;
    const int E = in_sizes[5] / 2;
    const int* src = ei;
    const int* dst = ei + E;

    char* p = (char*)d_ws;
    ushort* gb    = (ushort*)p; p += (size_t)N * 128 * sizeof(ushort);   // bf16 h (layer1) / g2 (layer2)
    ushort* tb    = (ushort*)p; p += (size_t)N * 128 * sizeof(ushort);   // bf16 layer-1 activation
    int*    cnt8  = (int*)p;    p += (size_t)8 * N * sizeof(int);        // per-XCD-part hist -> base8 (in-place)
    int*    off   = (int*)p;    p += (size_t)N * sizeof(int);
    int*    deg   = (int*)p;    p += (size_t)N * sizeof(int);
    float*  dinv  = (float*)p;  p += (size_t)N * sizeof(float);
    int*    srcs  = (int*)p;    p += (size_t)E * sizeof(int);
    int*    pos   = (int*)p;    p += (size_t)E * sizeof(int);
    ushort* Wt1   = (ushort*)p; p += 16384 * sizeof(ushort);
    ushort* Wt2   = (ushort*)p; p += 16384 * sizeof(ushort);
    int*    bsum  = (int*)p;    p += 1024;

    const int nb  = (N + 1023) / 1024;
    const int nbt = (N + 63) / 64;
    const int agg_blocks = ((size_t)N * 16 + NBLK - 1) / NBLK;   // 16 lanes/node

    hipMemsetAsync(cnt8, 0, (size_t)8 * N * sizeof(int), stream);
    wcast_k<<<128, NBLK, 0, stream>>>(W1, W2, Wt1, Wt2);

    // layer-1 GEMM (no dinv needed) + fused XCD-local degree count
    gemm_mfma_k<1, 0, 1><<<nbt, NBLK, 0, stream>>>(x, Wt1, nullptr, gb, N, dst, cnt8, pos, E);

    scan1_k<<<nb, NBLK, 0, stream>>>(cnt8, N, off, bsum);
    scan2_k<<<1, 128, 0, stream>>>(bsum, nb);
    scan3_k<<<(N + NBLK - 1) / NBLK, NBLK, 0, stream>>>(off, bsum, cnt8, deg, dinv, N);
    fill2_k<<<(E + NBLK - 1) / NBLK, NBLK, 0, stream>>>(src, dst, E, cnt8, pos, srcs, N);

    // layer-1 aggregate: per-src dinv, tanh, bf16 out
    aggregate_k<1, 1, 1><<<agg_blocks, NBLK, 0, stream>>>(gb, off, deg, srcs, dinv, b1, tb, N);
    // layer-2 GEMM: g2 = dinv * (tb @ W2)
    gemm_mfma_k<0, 1, 0><<<nbt, NBLK, 0, stream>>>(tb, Wt2, dinv, gb, N, nullptr, nullptr, nullptr, 0);
    // layer-2 aggregate: prescaled rows, f32 out
    aggregate_k<0, 0, 0><<<agg_blocks, NBLK, 0, stream>>>(gb, off, deg, srcs, dinv, b2, d_out, N);
}